// Round 9
// baseline (320.737 us; speedup 1.0000x reference)
//
#include <hip/hip_runtime.h>
#include <hip/hip_bf16.h>
#include <math.h>

#define B_   4
#define N_   6
#define CIN  512
#define CT   64
#define Dd   41
#define FH   16
#define FW   44
#define NPIX 704
#define NO   105
#define NOP  128          // padded output rows (bf16 weights)
#define DSTR 48           // featD per-pixel stride
#define NXX  128
#define NYY  128
#define NZZ  1
#define TOT  (B_*NZZ*NYY*NXX)   // 65536
#define NPTS (B_*N_*Dd*NPIX)    // 692736
#define NCHUNK ((NPTS+63)/64)   // 10824

#define PK_INVALID 0xFFFFFFFFu

#define XSTRIDE 72   // bf16 elems per s_xT row
#define WSTRIDE 72   // bf16 elems per s_wd row

typedef __attribute__((ext_vector_type(8))) short short8;
typedef __attribute__((ext_vector_type(4))) float f32x4;

// ---------------- helpers ----------------

__device__ __forceinline__ unsigned short f2bf(float f) {   // RNE
    unsigned u = __float_as_uint(f);
    u += 0x7FFFu + ((u >> 16) & 1u);
    return (unsigned short)(u >> 16);
}

__device__ __forceinline__ unsigned pack_bf2(float a, float c) {
    return (unsigned)f2bf(a) | ((unsigned)f2bf(c) << 16);
}

__device__ __forceinline__ void inv3(const double* m, double* o) {
    double a=m[0],b=m[1],c=m[2],d=m[3],e=m[4],f=m[5],g=m[6],h=m[7],i=m[8];
    double A  =  (e*i - f*h);
    double Bc = -(d*i - f*g);
    double Cc =  (d*h - e*g);
    double det = a*A + b*Bc + c*Cc;
    double inv = 1.0/det;
    o[0]=A*inv;            o[1]=-(b*i - c*h)*inv;  o[2]= (b*f - c*e)*inv;
    o[3]=Bc*inv;           o[4]= (a*i - c*g)*inv;  o[5]=-(a*f - c*d)*inv;
    o[6]=Cc*inv;           o[7]=-(a*h - b*g)*inv;  o[8]= (a*e - b*d)*inv;
}

// in-wave same-key run info. All 64 lanes participate; invalid lanes must pass
// a unique key. leader = lane index of run start; runlen valid at leader.
__device__ __forceinline__ void run_info(unsigned key, int l,
                                         bool& isStart, int& leader, int& runlen) {
    unsigned keyp = __shfl(key, (l == 0) ? 0 : (l - 1));
    isStart = (l == 0) || (key != keyp);
    unsigned long long smask = __ballot(isStart);
    unsigned long long below = smask & ((2ULL << l) - 1ULL);   // bits 0..l
    leader = 63 - __clzll(below);
    unsigned long long above = (l == 63) ? 0ULL : (smask >> (l + 1));
    int nxt = above ? (l + 1 + __ffsll(above) - 1) : 64;
    runlen = nxt - l;
}

// ---------------- kernel P: prep = per-(b,n) transforms + Wd->bf16 ----------------
__global__ __launch_bounds__(256) void prep_kernel(
    const float* __restrict__ rots, const float* __restrict__ trans,
    const float* __restrict__ intrins, const float* __restrict__ post_rots,
    const float* __restrict__ post_trans, const float* __restrict__ Wd,
    double* __restrict__ tf, unsigned short* __restrict__ WdB)
{
    int idx = blockIdx.x * 256 + threadIdx.x;
    if (idx < NOP*CIN) {
        int o = idx / CIN;
        WdB[idx] = (o < NO) ? f2bf(Wd[idx]) : (unsigned short)0;
    }
    if (blockIdx.x == 0 && threadIdx.x < B_*N_) {
        int bn = threadIdx.x;
        double k[9], pr[9], r[9], ik[9], ipr[9], c[9];
        for (int i=0;i<9;i++) { k[i]=intrins[bn*9+i]; pr[i]=post_rots[bn*9+i]; r[i]=rots[bn*9+i]; }
        inv3(k, ik);
        inv3(pr, ipr);
        for (int i=0;i<3;i++)
            for (int j=0;j<3;j++) {
                double s = 0.0;
                for (int kk=0;kk<3;kk++) s += r[i*3+kk]*ik[kk*3+j];
                c[i*3+j] = s;
            }
        double* o = tf + bn*24;
        for (int i=0;i<9;i++) o[i]   = c[i];
        for (int i=0;i<9;i++) o[9+i] = ipr[i];
        for (int i=0;i<3;i++) o[18+i] = (double)trans[bn*3+i];
        for (int i=0;i<3;i++) o[21+i] = (double)post_trans[bn*3+i];
    }
}

// ---------------- kernel G: bf16 MFMA GEMM ----------------
// grid = 24 bn x 11 pixtiles x 4 osplits = 1056 blocks; block = 256 thr = 4 waves.
__global__ __launch_bounds__(256) void gemm_kernel(
    const float* __restrict__ x, const unsigned short* __restrict__ WdB,
    const float* __restrict__ bd,
    float* __restrict__ featD, float* __restrict__ featB)
{
    __shared__ unsigned short s_xT[64*XSTRIDE];   // [pix][k] bf16   9.2 KB
    __shared__ unsigned short s_wd[32*WSTRIDE];   // [o][k]  bf16    4.6 KB

    const int t    = threadIdx.x;
    const int l    = t & 63;
    const int wv   = t >> 6;
    const int col  = l & 15;
    const int quad = l >> 4;
    const int bn   = blockIdx.x / 44;
    const int r    = blockIdx.x % 44;
    const int tile = r % 11;
    const int s    = r / 11;          // osplit 0..3
    const int pix0 = tile * 64;

    f32x4 acc[2];
    acc[0] = (f32x4){0.f,0.f,0.f,0.f};
    acc[1] = (f32x4){0.f,0.f,0.f,0.f};

    const float* xb = x + (size_t)bn * CIN * NPIX + pix0;
    const unsigned* wsrc = (const unsigned*)WdB + (size_t)(s*32)*(CIN/2);

    for (int k0 = 0; k0 < CIN; k0 += 64) {
        {
            unsigned pkx[8];
            #pragma unroll
            for (int j = 0; j < 8; j++) {
                float a = xb[(size_t)(k0 + wv*16 + 2*j    )*NPIX + l];
                float c = xb[(size_t)(k0 + wv*16 + 2*j + 1)*NPIX + l];
                pkx[j] = pack_bf2(a, c);
            }
            unsigned* dst = (unsigned*)&s_xT[l*XSTRIDE + wv*16];
            *(uint4*)(dst + 0) = make_uint4(pkx[0],pkx[1],pkx[2],pkx[3]);
            *(uint4*)(dst + 4) = make_uint4(pkx[4],pkx[5],pkx[6],pkx[7]);
        }
        {
            uint4 v = *(const uint4*)(wsrc + (size_t)(t>>3)*(CIN/2) + (k0>>1) + (t&7)*4);
            *(uint4*)&s_wd[(t>>3)*WSTRIDE + (t&7)*8] = v;
        }
        __syncthreads();

        #pragma unroll
        for (int ks = 0; ks < 2; ks++) {
            short8 bfr = *(const short8*)&s_xT[(wv*16 + col)*XSTRIDE + quad*8 + ks*32];
            #pragma unroll
            for (int j = 0; j < 2; j++) {
                short8 afr = *(const short8*)&s_wd[(j*16 + col)*WSTRIDE + quad*8 + ks*32];
                acc[j] = __builtin_amdgcn_mfma_f32_16x16x32_bf16(afr, bfr, acc[j], 0, 0, 0);
            }
        }
        __syncthreads();
    }

    const int pix = pix0 + wv*16 + col;
    const size_t prow = (size_t)(bn*NPIX + pix);
    #pragma unroll
    for (int j = 0; j < 2; j++) {
        #pragma unroll
        for (int rr = 0; rr < 4; rr++) {
            int o = (2*s + j)*16 + quad*4 + rr;
            if (o < Dd) {
                featD[prow*DSTR + o] = acc[j][rr] + bd[o];
            } else if (o < NO) {
                featB[prow*CT + (o - Dd)] = acc[j][rr] + bd[o];
            }
        }
    }
}

// ---------------- kernel S1: geometry + pk + dedup hist ----------------
// grid = 24*176 blocks x 256 thr; wave = pixel; lane = depth.
__global__ __launch_bounds__(256) void geom_hist_kernel(
    const double* __restrict__ tf, unsigned* __restrict__ pk_arr,
    int* __restrict__ hist)
{
    __shared__ double s_tf[24];
    const int t   = threadIdx.x;
    const int l   = t & 63;
    const int wv  = t >> 6;
    const int bn  = blockIdx.x / 176;
    const int pix = (blockIdx.x % 176)*4 + wv;
    const int b   = bn / N_;

    if (t < 24) s_tf[t] = tf[bn*24 + t];
    __syncthreads();

    const size_t prow = (size_t)(bn*NPIX + pix);

    const int hh = pix / FW, ww = pix % FW;
    const double fx = (double)((float)(ww * (703.0/43.0)));
    const double fy = (double)((float)(hh * 17.0));
    const double px = fx - s_tf[21], py = fy - s_tf[22], mz = -s_tf[23];
    const double qx0 = s_tf[ 9]*px + s_tf[10]*py + s_tf[11]*mz, qx1 = s_tf[11];
    const double qy0 = s_tf[12]*px + s_tf[13]*py + s_tf[14]*mz, qy1 = s_tf[14];
    const double qz0 = s_tf[15]*px + s_tf[16]*py + s_tf[17]*mz, qz1 = s_tf[17];
    const double ux0 = s_tf[0]*qx0 + s_tf[1]*qy0 + s_tf[2], ux1 = s_tf[0]*qx1 + s_tf[1]*qy1;
    const double uy0 = s_tf[3]*qx0 + s_tf[4]*qy0 + s_tf[5], uy1 = s_tf[3]*qx1 + s_tf[4]*qy1;
    const double uz0 = s_tf[6]*qx0 + s_tf[7]*qy0 + s_tf[8], uz1 = s_tf[6]*qx1 + s_tf[7]*qy1;
    const double t0 = s_tf[18], t1 = s_tf[19], t2 = s_tf[20];

    const double DXD = (double)0.8f;
    const double LOX = (double)(-50.8f) - DXD*0.5;
    const double LOY = LOX;
    const double DZD = 20.0;
    const double LOZ = -10.0;

    bool kept = false;
    int  vox  = 0;
    if (l < Dd) {
        double fz = 4.0 + (double)l;
        double qz = qz0 + qz1*fz;
        double sx = qz*(ux0 + ux1*fz) + t0;
        double sy = qz*(uy0 + uy1*fz) + t1;
        double sz = qz*(uz0 + uz1*fz) + t2;
        int gx = (int)((sx - LOX) / DXD);
        int gy = (int)((sy - LOY) / DXD);
        int gz = (int)((sz - LOZ) / DZD);
        kept = (gx>=0) & (gx<NXX) & (gy>=0) & (gy<NYY) & (gz>=0) & (gz<NZZ);
        vox  = (((b*NZZ + gz)*NYY + gy)*NXX + gx);
        pk_arr[prow*Dd + l] = kept ? (((unsigned)vox << 15) | (unsigned)prow)
                                   : PK_INVALID;
    }

    // dedup histogram atomics: one add per same-voxel run
    unsigned key = kept ? (unsigned)vox : (0x80000000u | (unsigned)l);
    bool isStart; int leader, runlen;
    run_info(key, l, isStart, leader, runlen);
    if (isStart && kept) atomicAdd(&hist[vox], runlen);
}

// ---------------- kernel C: exclusive scan over 65536 bins -> cursor ----------------
__global__ __launch_bounds__(1024) void scan_kernel(const int* __restrict__ hist,
                                                    int* __restrict__ cursor) {
    __shared__ int s[1024];
    const int t = threadIdx.x;
    const int CHUNK = TOT / 1024;   // 64
    int base_idx = t * CHUNK;
    int sum = 0;
    int local[64];
    #pragma unroll 8
    for (int j=0;j<CHUNK;j++) { local[j] = hist[base_idx+j]; sum += local[j]; }
    s[t] = sum;
    __syncthreads();
    for (int off=1; off<1024; off<<=1) {
        int v = (t >= off) ? s[t-off] : 0;
        __syncthreads();
        s[t] += v;
        __syncthreads();
    }
    int run = (t==0) ? 0 : s[t-1];
    #pragma unroll 8
    for (int j=0;j<CHUNK;j++) {
        cursor[base_idx+j] = run;
        run += local[j];
    }
}

// ---------------- kernel S2: softmax + dedup-cursor scatter ----------------
// grid = 24*176 blocks x 256 thr; wave = pixel; lane = depth.
__global__ __launch_bounds__(256) void sm_scatter_kernel(
    const float* __restrict__ featD, const unsigned* __restrict__ pk_arr,
    int* __restrict__ cursor, unsigned* __restrict__ spk,
    float* __restrict__ sw)
{
    const int t   = threadIdx.x;
    const int l   = t & 63;
    const int wv  = t >> 6;
    const int bn  = blockIdx.x / 176;
    const int pix = (blockIdx.x % 176)*4 + wv;

    const size_t prow = (size_t)(bn*NPIX + pix);

    // ---- softmax across lanes (d = lane, 41 active) ----
    float logit = (l < Dd) ? featD[prow*DSTR + l] : -3.0e38f;
    float mm = logit;
    #pragma unroll
    for (int off = 32; off > 0; off >>= 1) mm = fmaxf(mm, __shfl_xor(mm, off));
    float e = (l < Dd) ? expf(logit - mm) : 0.0f;
    float ssum = e;
    #pragma unroll
    for (int off = 32; off > 0; off >>= 1) ssum += __shfl_xor(ssum, off);
    const float wgt = e / ssum;

    // ---- read pk, dedup cursor reserve, scatter ----
    unsigned pk = (l < Dd) ? pk_arr[prow*Dd + l] : PK_INVALID;
    bool kept = (pk != PK_INVALID);
    unsigned vox = pk >> 15;
    unsigned key = kept ? vox : (0x80000000u | (unsigned)l);
    bool isStart; int leader, runlen;
    run_info(key, l, isStart, leader, runlen);
    int base = 0;
    if (isStart && kept) base = atomicAdd(&cursor[vox], runlen);
    int lbase = __shfl(base, leader);
    if (kept) {
        int pos = lbase + (l - leader);
        spk[pos] = pk;
        sw[pos]  = wgt;
    }
}

// ---------------- kernel E: balanced segmented gather -> scat[vox][ct] ----------------
__global__ __launch_bounds__(256) void gather_kernel(
    const unsigned* __restrict__ spk, const float* __restrict__ sw,
    const int* __restrict__ cursor, const float* __restrict__ featB,
    float* __restrict__ scat)
{
    const int t  = threadIdx.x;
    const int wv = t >> 6;
    const int l  = t & 63;
    const int chunk = blockIdx.x * 4 + wv;
    const int base  = chunk * 64;
    const int Np = cursor[TOT-1];          // total valid points
    if (base >= Np) return;
    int cnt = Np - base; if (cnt > 64) cnt = 64;

    unsigned pk = 0; float w = 0.0f;
    if (l < cnt) { pk = spk[base + l]; w = sw[base + l]; }
    unsigned pkm = __shfl(pk, (l == 0) ? 0 : (l - 1));
    unsigned long long starts =
        __ballot((l > 0) && (l < cnt) && ((pk >> 15) != (pkm >> 15)));

    unsigned long long m = starts;
    int rs = 0;
    while (rs < cnt) {
        int re = m ? (__ffsll((unsigned long long)m) - 1) : cnt;
        if (m) m &= m - 1;
        float acc = 0.0f;
        for (int j = rs; j < re; j++) {
            unsigned pkj = __shfl(pk, j);
            float    wj  = __shfl(w, j);
            unsigned id  = pkj & 0x7FFFu;
            acc += wj * featB[(size_t)id * CT + l];
        }
        unsigned vrun = __shfl(pk, rs) >> 15;
        float* dst = scat + (size_t)vrun * CT + l;
        if (rs == 0 || re == cnt) {
            unsafeAtomicAdd(dst, acc);      // run may continue in adjacent chunk
        } else {
            *dst = acc;                     // voxel wholly owned by this chunk
        }
        rs = re;
    }
}

// ---------------- kernel F: transpose (b,pix,ct) -> (b,ct,pix) ----------------
__global__ __launch_bounds__(256) void transpose_k(const float* __restrict__ scat,
                                                   float* __restrict__ out) {
    __shared__ float tile[64][65];
    int b  = blockIdx.x >> 8;
    int t0 = (blockIdx.x & 255) * 64;
    const float* src = scat + (size_t)b * (NYY*NXX) * CT;
    #pragma unroll
    for (int i=0;i<16;i++) {
        int idx = threadIdx.x + i*256;
        int p = idx >> 6, c = idx & 63;
        tile[p][c] = src[(size_t)(t0+p)*CT + c];
    }
    __syncthreads();
    float* dst = out + (size_t)b * CT * (NYY*NXX);
    #pragma unroll
    for (int i=0;i<16;i++) {
        int idx = threadIdx.x + i*256;
        int c = idx >> 6, p = idx & 63;
        dst[(size_t)c*(NYY*NXX) + t0 + p] = tile[p][c];
    }
}

// ---------------- launcher ----------------
extern "C" void kernel_launch(void* const* d_in, const int* in_sizes, int n_in,
                              void* d_out, int out_size, void* d_ws, size_t ws_size,
                              hipStream_t stream) {
    const float* x          = (const float*)d_in[0];
    const float* rots       = (const float*)d_in[1];
    const float* trans      = (const float*)d_in[2];
    const float* intrins    = (const float*)d_in[3];
    const float* post_rots  = (const float*)d_in[4];
    const float* post_trans = (const float*)d_in[5];
    const float* Wd         = (const float*)d_in[6];
    const float* bd         = (const float*)d_in[7];
    float* out = (float*)d_out;

    char* ws = (char*)d_ws;
    float*          featB  = (float*)ws;          ws += (size_t)B_*N_*NPIX*CT*4;    // 4.33 MB
    float*          featD  = (float*)ws;          ws += (size_t)B_*N_*NPIX*DSTR*4;  // 3.25 MB
    unsigned*       pk_arr = (unsigned*)ws;       ws += (size_t)NPTS*4;             // 2.77 MB
    unsigned*       spk    = (unsigned*)ws;       ws += (size_t)NPTS*4;             // 2.77 MB
    float*          sw     = (float*)ws;          ws += (size_t)NPTS*4;             // 2.77 MB
    float*          scat   = (float*)ws;          ws += (size_t)TOT*CT*4;           // 16.78 MB
    int*            hist   = (int*)ws;            ws += (size_t)TOT*4;              // 0.26 MB
    int*            cursor = (int*)ws;            ws += (size_t)TOT*4;              // 0.26 MB
    double*         tf     = (double*)ws;         ws += (size_t)B_*N_*24*8;         // 4.6 KB
    unsigned short* WdB    = (unsigned short*)ws; ws += (size_t)NOP*CIN*2;          // 0.13 MB

    hipMemsetAsync(scat, 0, (size_t)TOT*CT*4, stream);
    hipMemsetAsync(hist, 0, (size_t)TOT*4, stream);
    prep_kernel<<<(NOP*CIN+255)/256, 256, 0, stream>>>(rots, trans, intrins, post_rots,
                                                       post_trans, Wd, tf, WdB);
    gemm_kernel<<<B_*N_*44, 256, 0, stream>>>(x, WdB, bd, featD, featB);
    geom_hist_kernel<<<B_*N_*176, 256, 0, stream>>>(tf, pk_arr, hist);
    scan_kernel<<<1, 1024, 0, stream>>>(hist, cursor);
    sm_scatter_kernel<<<B_*N_*176, 256, 0, stream>>>(featD, pk_arr, cursor, spk, sw);
    gather_kernel<<<(NCHUNK+3)/4, 256, 0, stream>>>(spk, sw, cursor, featB, scat);
    transpose_k<<<B_*(NYY*NXX/64), 256, 0, stream>>>(scat, out);
}

// Round 10
// 296.867 us; speedup vs baseline: 1.0804x; 1.0804x over previous
//
#include <hip/hip_runtime.h>
#include <hip/hip_bf16.h>
#include <math.h>

#define B_   4
#define N_   6
#define CIN  512
#define CT   64
#define Dd   41
#define FH   16
#define FW   44
#define NPIX 704
#define NO   105
#define NOP  128          // padded output rows (bf16 weights)
#define DSTR 48           // featD per-pixel stride
#define NXX  128
#define NYY  128
#define NZZ  1
#define TOT  (B_*NZZ*NYY*NXX)   // 65536
#define NPTS (B_*N_*Dd*NPIX)    // 692736
#define NCHUNK ((NPTS+63)/64)   // 10824

#define XSTRIDE 72   // bf16 elems per s_xT row
#define WSTRIDE 72   // bf16 elems per s_wd row

typedef __attribute__((ext_vector_type(8))) short short8;
typedef __attribute__((ext_vector_type(4))) float f32x4;

// ---------------- helpers ----------------

__device__ __forceinline__ unsigned short f2bf(float f) {   // RNE
    unsigned u = __float_as_uint(f);
    u += 0x7FFFu + ((u >> 16) & 1u);
    return (unsigned short)(u >> 16);
}

__device__ __forceinline__ unsigned pack_bf2(float a, float c) {
    return (unsigned)f2bf(a) | ((unsigned)f2bf(c) << 16);
}

__device__ __forceinline__ void inv3(const double* m, double* o) {
    double a=m[0],b=m[1],c=m[2],d=m[3],e=m[4],f=m[5],g=m[6],h=m[7],i=m[8];
    double A  =  (e*i - f*h);
    double Bc = -(d*i - f*g);
    double Cc =  (d*h - e*g);
    double det = a*A + b*Bc + c*Cc;
    double inv = 1.0/det;
    o[0]=A*inv;            o[1]=-(b*i - c*h)*inv;  o[2]= (b*f - c*e)*inv;
    o[3]=Bc*inv;           o[4]= (a*i - c*g)*inv;  o[5]=-(a*f - c*d)*inv;
    o[6]=Cc*inv;           o[7]=-(a*h - b*g)*inv;  o[8]= (a*e - b*d)*inv;
}

// geometry for lane l (= depth) of pixel pix, camera bn. returns kept/vox.
__device__ __forceinline__ void geom_lane(const double* s_tf, int b, int pix, int l,
                                          bool& kept, int& vox) {
    const int hh = pix / FW, ww = pix % FW;
    const double fx = (double)((float)(ww * (703.0/43.0)));
    const double fy = (double)((float)(hh * 17.0));
    const double px = fx - s_tf[21], py = fy - s_tf[22], mz = -s_tf[23];
    const double qx0 = s_tf[ 9]*px + s_tf[10]*py + s_tf[11]*mz, qx1 = s_tf[11];
    const double qy0 = s_tf[12]*px + s_tf[13]*py + s_tf[14]*mz, qy1 = s_tf[14];
    const double qz0 = s_tf[15]*px + s_tf[16]*py + s_tf[17]*mz, qz1 = s_tf[17];
    const double ux0 = s_tf[0]*qx0 + s_tf[1]*qy0 + s_tf[2], ux1 = s_tf[0]*qx1 + s_tf[1]*qy1;
    const double uy0 = s_tf[3]*qx0 + s_tf[4]*qy0 + s_tf[5], uy1 = s_tf[3]*qx1 + s_tf[4]*qy1;
    const double uz0 = s_tf[6]*qx0 + s_tf[7]*qy0 + s_tf[8], uz1 = s_tf[6]*qx1 + s_tf[7]*qy1;
    const double t0 = s_tf[18], t1 = s_tf[19], t2 = s_tf[20];

    const double DXD = (double)0.8f;
    const double LOX = (double)(-50.8f) - DXD*0.5;
    const double LOY = LOX;
    const double DZD = 20.0;
    const double LOZ = -10.0;

    kept = false; vox = 0;
    if (l < Dd) {
        double fz = 4.0 + (double)l;
        double qz = qz0 + qz1*fz;
        double sx = qz*(ux0 + ux1*fz) + t0;
        double sy = qz*(uy0 + uy1*fz) + t1;
        double sz = qz*(uz0 + uz1*fz) + t2;
        int gx = (int)((sx - LOX) / DXD);
        int gy = (int)((sy - LOY) / DXD);
        int gz = (int)((sz - LOZ) / DZD);
        kept = (gx>=0) & (gx<NXX) & (gy>=0) & (gy<NYY) & (gz>=0) & (gz<NZZ);
        vox  = (((b*NZZ + gz)*NYY + gy)*NXX + gx);
    }
}

// ---------------- kernel P: prep = per-(b,n) transforms + Wd->bf16 ----------------
__global__ __launch_bounds__(256) void prep_kernel(
    const float* __restrict__ rots, const float* __restrict__ trans,
    const float* __restrict__ intrins, const float* __restrict__ post_rots,
    const float* __restrict__ post_trans, const float* __restrict__ Wd,
    double* __restrict__ tf, unsigned short* __restrict__ WdB)
{
    int idx = blockIdx.x * 256 + threadIdx.x;
    if (idx < NOP*CIN) {
        int o = idx / CIN;
        WdB[idx] = (o < NO) ? f2bf(Wd[idx]) : (unsigned short)0;
    }
    if (blockIdx.x == 0 && threadIdx.x < B_*N_) {
        int bn = threadIdx.x;
        double k[9], pr[9], r[9], ik[9], ipr[9], c[9];
        for (int i=0;i<9;i++) { k[i]=intrins[bn*9+i]; pr[i]=post_rots[bn*9+i]; r[i]=rots[bn*9+i]; }
        inv3(k, ik);
        inv3(pr, ipr);
        for (int i=0;i<3;i++)
            for (int j=0;j<3;j++) {
                double s = 0.0;
                for (int kk=0;kk<3;kk++) s += r[i*3+kk]*ik[kk*3+j];
                c[i*3+j] = s;
            }
        double* o = tf + bn*24;
        for (int i=0;i<9;i++) o[i]   = c[i];
        for (int i=0;i<9;i++) o[9+i] = ipr[i];
        for (int i=0;i<3;i++) o[18+i] = (double)trans[bn*3+i];
        for (int i=0;i<3;i++) o[21+i] = (double)post_trans[bn*3+i];
    }
}

// ---------------- kernel G: bf16 MFMA GEMM ----------------
// grid = 24 bn x 11 pixtiles x 4 osplits = 1056 blocks; block = 256 thr = 4 waves.
__global__ __launch_bounds__(256) void gemm_kernel(
    const float* __restrict__ x, const unsigned short* __restrict__ WdB,
    const float* __restrict__ bd,
    float* __restrict__ featD, float* __restrict__ featB)
{
    __shared__ unsigned short s_xT[64*XSTRIDE];   // [pix][k] bf16   9.2 KB
    __shared__ unsigned short s_wd[32*WSTRIDE];   // [o][k]  bf16    4.6 KB

    const int t    = threadIdx.x;
    const int l    = t & 63;
    const int wv   = t >> 6;
    const int col  = l & 15;
    const int quad = l >> 4;
    const int bn   = blockIdx.x / 44;
    const int r    = blockIdx.x % 44;
    const int tile = r % 11;
    const int s    = r / 11;          // osplit 0..3
    const int pix0 = tile * 64;

    f32x4 acc[2];
    acc[0] = (f32x4){0.f,0.f,0.f,0.f};
    acc[1] = (f32x4){0.f,0.f,0.f,0.f};

    const float* xb = x + (size_t)bn * CIN * NPIX + pix0;
    const unsigned* wsrc = (const unsigned*)WdB + (size_t)(s*32)*(CIN/2);

    for (int k0 = 0; k0 < CIN; k0 += 64) {
        {
            unsigned pkx[8];
            #pragma unroll
            for (int j = 0; j < 8; j++) {
                float a = xb[(size_t)(k0 + wv*16 + 2*j    )*NPIX + l];
                float c = xb[(size_t)(k0 + wv*16 + 2*j + 1)*NPIX + l];
                pkx[j] = pack_bf2(a, c);
            }
            unsigned* dst = (unsigned*)&s_xT[l*XSTRIDE + wv*16];
            *(uint4*)(dst + 0) = make_uint4(pkx[0],pkx[1],pkx[2],pkx[3]);
            *(uint4*)(dst + 4) = make_uint4(pkx[4],pkx[5],pkx[6],pkx[7]);
        }
        {
            uint4 v = *(const uint4*)(wsrc + (size_t)(t>>3)*(CIN/2) + (k0>>1) + (t&7)*4);
            *(uint4*)&s_wd[(t>>3)*WSTRIDE + (t&7)*8] = v;
        }
        __syncthreads();

        #pragma unroll
        for (int ks = 0; ks < 2; ks++) {
            short8 bfr = *(const short8*)&s_xT[(wv*16 + col)*XSTRIDE + quad*8 + ks*32];
            #pragma unroll
            for (int j = 0; j < 2; j++) {
                short8 afr = *(const short8*)&s_wd[(j*16 + col)*WSTRIDE + quad*8 + ks*32];
                acc[j] = __builtin_amdgcn_mfma_f32_16x16x32_bf16(afr, bfr, acc[j], 0, 0, 0);
            }
        }
        __syncthreads();
    }

    const int pix = pix0 + wv*16 + col;
    const size_t prow = (size_t)(bn*NPIX + pix);
    #pragma unroll
    for (int j = 0; j < 2; j++) {
        #pragma unroll
        for (int rr = 0; rr < 4; rr++) {
            int o = (2*s + j)*16 + quad*4 + rr;
            if (o < Dd) {
                featD[prow*DSTR + o] = acc[j][rr] + bd[o];
            } else if (o < NO) {
                featB[prow*CT + (o - Dd)] = acc[j][rr] + bd[o];
            }
        }
    }
}

// ---------------- kernel S1: geometry -> hist ----------------
// grid = 4224 blocks (XCD-swizzled) x 256 thr; wave = pixel; lane = depth.
__global__ __launch_bounds__(256) void geom_hist_kernel(
    const double* __restrict__ tf, int* __restrict__ hist)
{
    __shared__ double s_tf[24];
    const int bid = (blockIdx.x & 7) * 528 + (blockIdx.x >> 3);   // XCD locality
    const int t   = threadIdx.x;
    const int l   = t & 63;
    const int wv  = t >> 6;
    const int bn  = bid / 176;
    const int pix = (bid % 176)*4 + wv;
    const int b   = bn / N_;

    if (t < 24) s_tf[t] = tf[bn*24 + t];
    __syncthreads();

    bool kept; int vox;
    geom_lane(s_tf, b, pix, l, kept, vox);
    if (kept) atomicAdd(&hist[vox], 1);
}

// ---------------- kernel C: exclusive scan over 65536 bins -> cursor ----------------
__global__ __launch_bounds__(1024) void scan_kernel(const int* __restrict__ hist,
                                                    int* __restrict__ cursor) {
    __shared__ int s[1024];
    const int t = threadIdx.x;
    const int CHUNK = TOT / 1024;   // 64
    int base_idx = t * CHUNK;
    int sum = 0;
    int local[64];
    #pragma unroll 8
    for (int j=0;j<CHUNK;j++) { local[j] = hist[base_idx+j]; sum += local[j]; }
    s[t] = sum;
    __syncthreads();
    for (int off=1; off<1024; off<<=1) {
        int v = (t >= off) ? s[t-off] : 0;
        __syncthreads();
        s[t] += v;
        __syncthreads();
    }
    int run = (t==0) ? 0 : s[t-1];
    #pragma unroll 8
    for (int j=0;j<CHUNK;j++) {
        cursor[base_idx+j] = run;
        run += local[j];
    }
}

// ---------------- kernel S2: softmax + geometry + record scatter ----------------
// grid = 4224 blocks (XCD-swizzled) x 256 thr; wave = pixel; lane = depth.
__global__ __launch_bounds__(256) void sm_scatter_kernel(
    const float* __restrict__ featD, const double* __restrict__ tf,
    int* __restrict__ cursor, uint2* __restrict__ rec)
{
    __shared__ double s_tf[24];
    const int bid = (blockIdx.x & 7) * 528 + (blockIdx.x >> 3);   // XCD locality
    const int t   = threadIdx.x;
    const int l   = t & 63;
    const int wv  = t >> 6;
    const int bn  = bid / 176;
    const int pix = (bid % 176)*4 + wv;
    const int b   = bn / N_;

    if (t < 24) s_tf[t] = tf[bn*24 + t];
    __syncthreads();

    const size_t prow = (size_t)(bn*NPIX + pix);

    // ---- softmax across lanes (d = lane, 41 active) ----
    float logit = (l < Dd) ? featD[prow*DSTR + l] : -3.0e38f;
    float mm = logit;
    #pragma unroll
    for (int off = 32; off > 0; off >>= 1) mm = fmaxf(mm, __shfl_xor(mm, off));
    float e = (l < Dd) ? expf(logit - mm) : 0.0f;
    float ssum = e;
    #pragma unroll
    for (int off = 32; off > 0; off >>= 1) ssum += __shfl_xor(ssum, off);
    const float wgt = e / ssum;

    // ---- geometry (recomputed in-register) + scatter one 8B record ----
    bool kept; int vox;
    geom_lane(s_tf, b, pix, l, kept, vox);
    if (kept) {
        unsigned pk = ((unsigned)vox << 15) | (unsigned)prow;
        int pos = atomicAdd(&cursor[vox], 1);
        rec[pos] = make_uint2(pk, __float_as_uint(wgt));
    }
}

// ---------------- kernel E: balanced segmented gather -> scat[vox][ct] ----------------
// grid = 2712 blocks (XCD-swizzled) x 4 waves; wave = 64-record chunk.
__global__ __launch_bounds__(256) void gather_kernel(
    const uint2* __restrict__ rec, const int* __restrict__ cursor,
    const float* __restrict__ featB, float* __restrict__ scat)
{
    const int bid = (blockIdx.x & 7) * 339 + (blockIdx.x >> 3);   // XCD locality
    const int t  = threadIdx.x;
    const int wv = t >> 6;
    const int l  = t & 63;
    const int chunk = bid * 4 + wv;
    const int base  = chunk * 64;
    const int Np = cursor[TOT-1];          // total valid points
    if (base >= Np) return;
    int cnt = Np - base; if (cnt > 64) cnt = 64;

    unsigned pk = 0; float w = 0.0f;
    if (l < cnt) { uint2 r = rec[base + l]; pk = r.x; w = __uint_as_float(r.y); }
    unsigned pkm = __shfl(pk, (l == 0) ? 0 : (l - 1));
    unsigned long long starts =
        __ballot((l > 0) && (l < cnt) && ((pk >> 15) != (pkm >> 15)));

    unsigned long long m = starts;
    int rs = 0;
    while (rs < cnt) {
        int re = m ? (__ffsll((unsigned long long)m) - 1) : cnt;
        if (m) m &= m - 1;
        float acc = 0.0f;
        for (int j = rs; j < re; j++) {
            unsigned pkj = __shfl(pk, j);
            float    wj  = __shfl(w, j);
            unsigned id  = pkj & 0x7FFFu;
            acc += wj * featB[(size_t)id * CT + l];
        }
        unsigned vrun = __shfl(pk, rs) >> 15;
        float* dst = scat + (size_t)vrun * CT + l;
        if (rs == 0 || re == cnt) {
            unsafeAtomicAdd(dst, acc);      // run may continue in adjacent chunk
        } else {
            *dst = acc;                     // voxel wholly owned by this chunk
        }
        rs = re;
    }
}

// ---------------- kernel F: transpose (b,pix,ct) -> (b,ct,pix) ----------------
__global__ __launch_bounds__(256) void transpose_k(const float* __restrict__ scat,
                                                   float* __restrict__ out) {
    __shared__ float tile[64][65];
    int b  = blockIdx.x >> 8;
    int t0 = (blockIdx.x & 255) * 64;
    const float* src = scat + (size_t)b * (NYY*NXX) * CT;
    #pragma unroll
    for (int i=0;i<16;i++) {
        int idx = threadIdx.x + i*256;
        int p = idx >> 6, c = idx & 63;
        tile[p][c] = src[(size_t)(t0+p)*CT + c];
    }
    __syncthreads();
    float* dst = out + (size_t)b * CT * (NYY*NXX);
    #pragma unroll
    for (int i=0;i<16;i++) {
        int idx = threadIdx.x + i*256;
        int c = idx >> 6, p = idx & 63;
        dst[(size_t)c*(NYY*NXX) + t0 + p] = tile[p][c];
    }
}

// ---------------- launcher ----------------
extern "C" void kernel_launch(void* const* d_in, const int* in_sizes, int n_in,
                              void* d_out, int out_size, void* d_ws, size_t ws_size,
                              hipStream_t stream) {
    const float* x          = (const float*)d_in[0];
    const float* rots       = (const float*)d_in[1];
    const float* trans      = (const float*)d_in[2];
    const float* intrins    = (const float*)d_in[3];
    const float* post_rots  = (const float*)d_in[4];
    const float* post_trans = (const float*)d_in[5];
    const float* Wd         = (const float*)d_in[6];
    const float* bd         = (const float*)d_in[7];
    float* out = (float*)d_out;

    char* ws = (char*)d_ws;
    float*          featB  = (float*)ws;          ws += (size_t)B_*N_*NPIX*CT*4;    // 4.33 MB
    float*          featD  = (float*)ws;          ws += (size_t)B_*N_*NPIX*DSTR*4;  // 3.25 MB
    uint2*          rec    = (uint2*)ws;          ws += (size_t)NPTS*8;             // 5.54 MB
    float*          scat   = (float*)ws;          ws += (size_t)TOT*CT*4;           // 16.78 MB
    int*            hist   = (int*)ws;            ws += (size_t)TOT*4;              // 0.26 MB
    int*            cursor = (int*)ws;            ws += (size_t)TOT*4;              // 0.26 MB
    double*         tf     = (double*)ws;         ws += (size_t)B_*N_*24*8;         // 4.6 KB
    unsigned short* WdB    = (unsigned short*)ws; ws += (size_t)NOP*CIN*2;          // 0.13 MB

    hipMemsetAsync(scat, 0, (size_t)TOT*CT*4, stream);
    hipMemsetAsync(hist, 0, (size_t)TOT*4, stream);
    prep_kernel<<<(NOP*CIN+255)/256, 256, 0, stream>>>(rots, trans, intrins, post_rots,
                                                       post_trans, Wd, tf, WdB);
    gemm_kernel<<<B_*N_*44, 256, 0, stream>>>(x, WdB, bd, featD, featB);
    geom_hist_kernel<<<B_*N_*176, 256, 0, stream>>>(tf, hist);
    scan_kernel<<<1, 1024, 0, stream>>>(hist, cursor);
    sm_scatter_kernel<<<B_*N_*176, 256, 0, stream>>>(featD, tf, cursor, rec);
    gather_kernel<<<2712, 256, 0, stream>>>(rec, cursor, featB, scat);
    transpose_k<<<B_*(NYY*NXX/64), 256, 0, stream>>>(scat, out);
}

// Round 11
// 258.731 us; speedup vs baseline: 1.2397x; 1.1474x over previous
//
#include <hip/hip_runtime.h>
#include <hip/hip_bf16.h>
#include <math.h>

#define B_   4
#define N_   6
#define CIN  512
#define CT   64
#define Dd   41
#define FH   16
#define FW   44
#define NPIX 704
#define NO   105
#define DSTR 48           // featD per-pixel stride
#define NXX  128
#define NYY  128
#define NZZ  1
#define TOT  (B_*NZZ*NYY*NXX)   // 65536
#define NPTS (B_*N_*Dd*NPIX)    // 692736
#define NCHUNK ((NPTS+63)/64)   // 10824

#define WSTRIDE 520  // bf16 elems per s_wd row (512 + 8 pad)

typedef __attribute__((ext_vector_type(8))) short short8;
typedef __attribute__((ext_vector_type(4))) float f32x4;

// ---------------- helpers ----------------

__device__ __forceinline__ unsigned short f2bf(float f) {   // RNE
    unsigned u = __float_as_uint(f);
    u += 0x7FFFu + ((u >> 16) & 1u);
    return (unsigned short)(u >> 16);
}

__device__ __forceinline__ void inv3(const double* m, double* o) {
    double a=m[0],b=m[1],c=m[2],d=m[3],e=m[4],f=m[5],g=m[6],h=m[7],i=m[8];
    double A  =  (e*i - f*h);
    double Bc = -(d*i - f*g);
    double Cc =  (d*h - e*g);
    double det = a*A + b*Bc + c*Cc;
    double inv = 1.0/det;
    o[0]=A*inv;            o[1]=-(b*i - c*h)*inv;  o[2]= (b*f - c*e)*inv;
    o[3]=Bc*inv;           o[4]= (a*i - c*g)*inv;  o[5]=-(a*f - c*d)*inv;
    o[6]=Cc*inv;           o[7]=-(a*h - b*g)*inv;  o[8]= (a*e - b*d)*inv;
}

// geometry for lane l (= depth) of pixel pix, camera bn. returns kept/vox.
__device__ __forceinline__ void geom_lane(const double* s_tf, int b, int pix, int l,
                                          bool& kept, int& vox) {
    const int hh = pix / FW, ww = pix % FW;
    const double fx = (double)((float)(ww * (703.0/43.0)));
    const double fy = (double)((float)(hh * 17.0));
    const double px = fx - s_tf[21], py = fy - s_tf[22], mz = -s_tf[23];
    const double qx0 = s_tf[ 9]*px + s_tf[10]*py + s_tf[11]*mz, qx1 = s_tf[11];
    const double qy0 = s_tf[12]*px + s_tf[13]*py + s_tf[14]*mz, qy1 = s_tf[14];
    const double qz0 = s_tf[15]*px + s_tf[16]*py + s_tf[17]*mz, qz1 = s_tf[17];
    const double ux0 = s_tf[0]*qx0 + s_tf[1]*qy0 + s_tf[2], ux1 = s_tf[0]*qx1 + s_tf[1]*qy1;
    const double uy0 = s_tf[3]*qx0 + s_tf[4]*qy0 + s_tf[5], uy1 = s_tf[3]*qx1 + s_tf[4]*qy1;
    const double uz0 = s_tf[6]*qx0 + s_tf[7]*qy0 + s_tf[8], uz1 = s_tf[6]*qx1 + s_tf[7]*qy1;
    const double t0 = s_tf[18], t1 = s_tf[19], t2 = s_tf[20];

    const double DXD = (double)0.8f;
    const double LOX = (double)(-50.8f) - DXD*0.5;
    const double LOY = LOX;
    const double DZD = 20.0;
    const double LOZ = -10.0;

    kept = false; vox = 0;
    if (l < Dd) {
        double fz = 4.0 + (double)l;
        double qz = qz0 + qz1*fz;
        double sx = qz*(ux0 + ux1*fz) + t0;
        double sy = qz*(uy0 + uy1*fz) + t1;
        double sz = qz*(uz0 + uz1*fz) + t2;
        int gx = (int)((sx - LOX) / DXD);
        int gy = (int)((sy - LOY) / DXD);
        int gz = (int)((sz - LOZ) / DZD);
        kept = (gx>=0) & (gx<NXX) & (gy>=0) & (gy<NYY) & (gz>=0) & (gz<NZZ);
        vox  = (((b*NZZ + gz)*NYY + gy)*NXX + gx);
    }
}

// ---------------- kernel P: prep = x->bf16 fragment layout + Wd->bf16 + tf --------
// blocks 0..2111: xcvt (bn, kgroup of 64, pixtile of 64)
// blocks 2112..2367: WdB convert; block 2112 also computes tf.
// xB layout: bf16[ (bn*64 + k/8)*704 + pix ][ k%8 ]  (16B per (k8,pix) cell)
__global__ __launch_bounds__(256) void prep_kernel(
    const float* __restrict__ rots, const float* __restrict__ trans,
    const float* __restrict__ intrins, const float* __restrict__ post_rots,
    const float* __restrict__ post_trans, const float* __restrict__ Wd,
    const float* __restrict__ x,
    double* __restrict__ tf, unsigned short* __restrict__ WdB,
    unsigned short* __restrict__ xB)
{
    const int t = threadIdx.x;
    if (blockIdx.x < 2112) {
        __shared__ float s_x[64*65];
        const int p    = blockIdx.x;
        const int bn   = p / 88;
        const int r    = p % 88;
        const int kg   = r / 11;          // 0..7 (64 k each)
        const int tile = r % 11;
        const int pix0 = tile * 64;

        const float* src = x + ((size_t)bn*CIN + kg*64)*NPIX + pix0;
        #pragma unroll
        for (int i = 0; i < 16; i++) {
            int idx = i*256 + t;
            int k  = idx >> 6;
            int px = idx & 63;
            s_x[k*65 + px] = src[(size_t)k*NPIX + px];
        }
        __syncthreads();

        const int px  = t & 63;
        #pragma unroll
        for (int pass = 0; pass < 2; pass++) {
            int k8l = (t >> 6) + 4*pass;          // 0..7
            unsigned pk[4];
            #pragma unroll
            for (int i = 0; i < 4; i++) {
                float a = s_x[(k8l*8 + 2*i    )*65 + px];
                float c = s_x[(k8l*8 + 2*i + 1)*65 + px];
                pk[i] = (unsigned)f2bf(a) | ((unsigned)f2bf(c) << 16);
            }
            unsigned* dst = (unsigned*)&xB[(((size_t)(bn*64 + kg*8 + k8l))*NPIX + pix0 + px)*8];
            *(uint4*)dst = make_uint4(pk[0], pk[1], pk[2], pk[3]);
        }
    } else {
        int b2 = blockIdx.x - 2112;
        int idx = b2*256 + t;
        if (idx < 128*CIN) {
            int o = idx / CIN;
            WdB[idx] = (o < NO) ? f2bf(Wd[idx]) : (unsigned short)0;
        }
        if (b2 == 0 && t < B_*N_) {
            int bn = t;
            double k[9], pr[9], r[9], ik[9], ipr[9], c[9];
            for (int i=0;i<9;i++) { k[i]=intrins[bn*9+i]; pr[i]=post_rots[bn*9+i]; r[i]=rots[bn*9+i]; }
            inv3(k, ik);
            inv3(pr, ipr);
            for (int i=0;i<3;i++)
                for (int j=0;j<3;j++) {
                    double s = 0.0;
                    for (int kk=0;kk<3;kk++) s += r[i*3+kk]*ik[kk*3+j];
                    c[i*3+j] = s;
                }
            double* o = tf + bn*24;
            for (int i=0;i<9;i++) o[i]   = c[i];
            for (int i=0;i<9;i++) o[9+i] = ipr[i];
            for (int i=0;i<3;i++) o[18+i] = (double)trans[bn*3+i];
            for (int i=0;i<3;i++) o[21+i] = (double)post_trans[bn*3+i];
        }
    }
}

// ---------------- kernel G: bf16 MFMA GEMM, barrier-free K-loop ----------------
// 1056 blocks; xcd-grouped so the 4 osplits of one (bn,tile) share an XCD.
// Block: 256 thr = 4 waves (wave = 16 pixels); 32 outputs (osplit s).
__global__ __launch_bounds__(256) void gemm_kernel(
    const unsigned short* __restrict__ xB, const unsigned short* __restrict__ WdB,
    const float* __restrict__ bd,
    float* __restrict__ featD, float* __restrict__ featB)
{
    __shared__ unsigned short s_wd[32*WSTRIDE];   // 33.3 KB

    const int t    = threadIdx.x;
    const int l    = t & 63;
    const int wv   = t >> 6;
    const int col  = l & 15;
    const int quad = l >> 4;

    const int xcd = blockIdx.x & 7;
    const int q   = blockIdx.x >> 3;
    const int s   = q & 3;               // osplit
    const int pg  = q >> 2;
    const int p   = pg*8 + xcd;          // 0..263
    const int bn   = p / 11;
    const int tile = p % 11;
    const int pix0 = tile * 64;

    // ---- stage Wd rows s*32..s*32+31 (full K) into LDS, once ----
    {
        const int o  = t >> 3;           // 0..31
        const int c8 = t & 7;
        const unsigned short* srcw = WdB + (size_t)(s*32 + o)*CIN;
        #pragma unroll
        for (int i = 0; i < 8; i++) {
            int k = c8*8 + i*64;
            *(uint4*)&s_wd[o*WSTRIDE + k] = *(const uint4*)&srcw[k];
        }
    }
    __syncthreads();

    f32x4 acc[2];
    acc[0] = (f32x4){0.f,0.f,0.f,0.f};
    acc[1] = (f32x4){0.f,0.f,0.f,0.f};

    const int pix = pix0 + wv*16 + col;
    const unsigned short* xbase = xB + (((size_t)(bn*64) )*NPIX)*8;

    #pragma unroll
    for (int ks = 0; ks < 16; ks++) {
        const int k8 = ks*4 + quad;
        short8 bfr = *(const short8*)&xbase[((size_t)k8*NPIX + pix)*8];
        #pragma unroll
        for (int j = 0; j < 2; j++) {
            short8 afr = *(const short8*)&s_wd[(j*16 + col)*WSTRIDE + ks*32 + quad*8];
            acc[j] = __builtin_amdgcn_mfma_f32_16x16x32_bf16(afr, bfr, acc[j], 0, 0, 0);
        }
    }

    // ---- epilogue: D layout row=(quad*4+rr), col=lane&15 ----
    const size_t prow = (size_t)(bn*NPIX + pix);
    #pragma unroll
    for (int j = 0; j < 2; j++) {
        #pragma unroll
        for (int rr = 0; rr < 4; rr++) {
            int o = (2*s + j)*16 + quad*4 + rr;
            if (o < Dd) {
                featD[prow*DSTR + o] = acc[j][rr] + bd[o];
            } else if (o < NO) {
                featB[prow*CT + (o - Dd)] = acc[j][rr] + bd[o];
            }
        }
    }
}

// ---------------- kernel S1: geometry -> hist + per-point rank ----------------
// grid = 4224 blocks (XCD-swizzled) x 256 thr; wave = pixel; lane = depth.
__global__ __launch_bounds__(256) void geom_hist_kernel(
    const double* __restrict__ tf, int* __restrict__ hist,
    int* __restrict__ rank_arr)
{
    __shared__ double s_tf[24];
    const int bid = (blockIdx.x & 7) * 528 + (blockIdx.x >> 3);   // XCD locality
    const int t   = threadIdx.x;
    const int l   = t & 63;
    const int wv  = t >> 6;
    const int bn  = bid / 176;
    const int pix = (bid % 176)*4 + wv;
    const int b   = bn / N_;

    if (t < 24) s_tf[t] = tf[bn*24 + t];
    __syncthreads();

    bool kept; int vox;
    geom_lane(s_tf, b, pix, l, kept, vox);
    if (kept) {
        int rank = atomicAdd(&hist[vox], 1);
        rank_arr[(size_t)(bn*NPIX + pix)*Dd + l] = rank;
    }
}

// ---------------- kernel C: exclusive scan over 65536 bins -> offs, np ----------------
__global__ __launch_bounds__(1024) void scan_kernel(const int* __restrict__ hist,
                                                    int* __restrict__ offs,
                                                    int* __restrict__ np) {
    __shared__ int s[1024];
    const int t = threadIdx.x;
    const int CHUNK = TOT / 1024;   // 64
    int base_idx = t * CHUNK;
    int sum = 0;
    int local[64];
    #pragma unroll 8
    for (int j=0;j<CHUNK;j++) { local[j] = hist[base_idx+j]; sum += local[j]; }
    s[t] = sum;
    __syncthreads();
    for (int off=1; off<1024; off<<=1) {
        int v = (t >= off) ? s[t-off] : 0;
        __syncthreads();
        s[t] += v;
        __syncthreads();
    }
    if (t == 1023) np[0] = s[1023];
    int run = (t==0) ? 0 : s[t-1];
    #pragma unroll 8
    for (int j=0;j<CHUNK;j++) {
        offs[base_idx+j] = run;
        run += local[j];
    }
}

// ---------------- kernel S2: softmax + geometry + atomic-free record scatter --------
// grid = 4224 blocks (XCD-swizzled) x 256 thr; wave = pixel; lane = depth.
__global__ __launch_bounds__(256) void sm_scatter_kernel(
    const float* __restrict__ featD, const double* __restrict__ tf,
    const int* __restrict__ offs, const int* __restrict__ rank_arr,
    uint2* __restrict__ rec)
{
    __shared__ double s_tf[24];
    const int bid = (blockIdx.x & 7) * 528 + (blockIdx.x >> 3);   // XCD locality
    const int t   = threadIdx.x;
    const int l   = t & 63;
    const int wv  = t >> 6;
    const int bn  = bid / 176;
    const int pix = (bid % 176)*4 + wv;
    const int b   = bn / N_;

    if (t < 24) s_tf[t] = tf[bn*24 + t];
    __syncthreads();

    const size_t prow = (size_t)(bn*NPIX + pix);

    // ---- softmax across lanes (d = lane, 41 active) ----
    float logit = (l < Dd) ? featD[prow*DSTR + l] : -3.0e38f;
    float mm = logit;
    #pragma unroll
    for (int off = 32; off > 0; off >>= 1) mm = fmaxf(mm, __shfl_xor(mm, off));
    float e = (l < Dd) ? expf(logit - mm) : 0.0f;
    float ssum = e;
    #pragma unroll
    for (int off = 32; off > 0; off >>= 1) ssum += __shfl_xor(ssum, off);
    const float wgt = e / ssum;

    // ---- geometry + position from offs+rank (no atomics) ----
    bool kept; int vox;
    geom_lane(s_tf, b, pix, l, kept, vox);
    if (kept) {
        int pos = offs[vox] + rank_arr[prow*Dd + l];
        unsigned pk = ((unsigned)vox << 15) | (unsigned)prow;
        rec[pos] = make_uint2(pk, __float_as_uint(wgt));
    }
}

// ---------------- kernel E: balanced segmented gather -> scat[vox][ct] ----------------
// grid = 2712 blocks (XCD-swizzled) x 4 waves; wave = 64-record chunk.
__global__ __launch_bounds__(256) void gather_kernel(
    const uint2* __restrict__ rec, const int* __restrict__ np,
    const float* __restrict__ featB, float* __restrict__ scat)
{
    const int bid = (blockIdx.x & 7) * 339 + (blockIdx.x >> 3);   // XCD locality
    const int t  = threadIdx.x;
    const int wv = t >> 6;
    const int l  = t & 63;
    const int chunk = bid * 4 + wv;
    const int base  = chunk * 64;
    const int Np = np[0];                  // total valid points
    if (base >= Np) return;
    int cnt = Np - base; if (cnt > 64) cnt = 64;

    unsigned pk = 0; float w = 0.0f;
    if (l < cnt) { uint2 r = rec[base + l]; pk = r.x; w = __uint_as_float(r.y); }
    unsigned pkm = __shfl(pk, (l == 0) ? 0 : (l - 1));
    unsigned long long starts =
        __ballot((l > 0) && (l < cnt) && ((pk >> 15) != (pkm >> 15)));

    unsigned long long m = starts;
    int rs = 0;
    while (rs < cnt) {
        int re = m ? (__ffsll((unsigned long long)m) - 1) : cnt;
        if (m) m &= m - 1;
        float acc = 0.0f;
        for (int j = rs; j < re; j++) {
            unsigned pkj = __shfl(pk, j);
            float    wj  = __shfl(w, j);
            unsigned id  = pkj & 0x7FFFu;
            acc += wj * featB[(size_t)id * CT + l];
        }
        unsigned vrun = __shfl(pk, rs) >> 15;
        float* dst = scat + (size_t)vrun * CT + l;
        if (rs == 0 || re == cnt) {
            unsafeAtomicAdd(dst, acc);      // run may continue in adjacent chunk
        } else {
            *dst = acc;                     // voxel wholly owned by this chunk
        }
        rs = re;
    }
}

// ---------------- kernel F: transpose (b,pix,ct) -> (b,ct,pix) ----------------
__global__ __launch_bounds__(256) void transpose_k(const float* __restrict__ scat,
                                                   float* __restrict__ out) {
    __shared__ float tile[64][65];
    int b  = blockIdx.x >> 8;
    int t0 = (blockIdx.x & 255) * 64;
    const float* src = scat + (size_t)b * (NYY*NXX) * CT;
    #pragma unroll
    for (int i=0;i<16;i++) {
        int idx = threadIdx.x + i*256;
        int p = idx >> 6, c = idx & 63;
        tile[p][c] = src[(size_t)(t0+p)*CT + c];
    }
    __syncthreads();
    float* dst = out + (size_t)b * CT * (NYY*NXX);
    #pragma unroll
    for (int i=0;i<16;i++) {
        int idx = threadIdx.x + i*256;
        int c = idx >> 6, p = idx & 63;
        dst[(size_t)c*(NYY*NXX) + t0 + p] = tile[p][c];
    }
}

// ---------------- launcher ----------------
extern "C" void kernel_launch(void* const* d_in, const int* in_sizes, int n_in,
                              void* d_out, int out_size, void* d_ws, size_t ws_size,
                              hipStream_t stream) {
    const float* x          = (const float*)d_in[0];
    const float* rots       = (const float*)d_in[1];
    const float* trans      = (const float*)d_in[2];
    const float* intrins    = (const float*)d_in[3];
    const float* post_rots  = (const float*)d_in[4];
    const float* post_trans = (const float*)d_in[5];
    const float* Wd         = (const float*)d_in[6];
    const float* bd         = (const float*)d_in[7];
    float* out = (float*)d_out;

    char* ws = (char*)d_ws;
    float*          featB  = (float*)ws;          ws += (size_t)B_*N_*NPIX*CT*4;    // 4.33 MB
    float*          featD  = (float*)ws;          ws += (size_t)B_*N_*NPIX*DSTR*4;  // 3.25 MB
    char*           Xreg   = ws;                  ws += (size_t)B_*N_*CIN*NPIX*2;   // 17.3 MB (xB, then scat)
    int*            rank_a = (int*)ws;            ws += (size_t)NPTS*4;             // 2.77 MB
    uint2*          rec    = (uint2*)ws;          ws += (size_t)NPTS*8;             // 5.54 MB
    int*            hist   = (int*)ws;            ws += (size_t)TOT*4;              // 0.26 MB
    int*            offs   = (int*)ws;            ws += (size_t)TOT*4;              // 0.26 MB
    int*            np     = (int*)ws;            ws += 256;
    double*         tf     = (double*)ws;         ws += (size_t)B_*N_*24*8;         // 4.6 KB
    unsigned short* WdB    = (unsigned short*)ws; ws += (size_t)128*CIN*2;          // 0.13 MB

    unsigned short* xB   = (unsigned short*)Xreg;
    float*          scat = (float*)Xreg;   // reuses xB region after gemm

    hipMemsetAsync(hist, 0, (size_t)TOT*4, stream);
    prep_kernel<<<2368, 256, 0, stream>>>(rots, trans, intrins, post_rots, post_trans,
                                          Wd, x, tf, WdB, xB);
    gemm_kernel<<<1056, 256, 0, stream>>>(xB, WdB, bd, featD, featB);
    geom_hist_kernel<<<B_*N_*176, 256, 0, stream>>>(tf, hist, rank_a);
    hipMemsetAsync(scat, 0, (size_t)TOT*CT*4, stream);      // xB dead after gemm
    scan_kernel<<<1, 1024, 0, stream>>>(hist, offs, np);
    sm_scatter_kernel<<<B_*N_*176, 256, 0, stream>>>(featD, tf, offs, rank_a, rec);
    gather_kernel<<<2712, 256, 0, stream>>>(rec, np, featB, scat);
    transpose_k<<<B_*(NYY*NXX/64), 256, 0, stream>>>(scat, out);
}

// Round 12
// 220.883 us; speedup vs baseline: 1.4521x; 1.1713x over previous
//
#include <hip/hip_runtime.h>
#include <hip/hip_bf16.h>
#include <math.h>

#define B_   4
#define N_   6
#define CIN  512
#define CT   64
#define Dd   41
#define FH   16
#define FW   44
#define NPIX 704
#define NO   105
#define DSTR 48           // featD per-pixel stride
#define NXX  128
#define NYY  128
#define NZZ  1
#define TOT  (B_*NZZ*NYY*NXX)   // 65536
#define NK   (TOT*8)            // 524288 sub-histogram keys
#define NPTS (B_*N_*Dd*NPIX)    // 692736
#define NCHUNK ((NPTS+63)/64)   // 10824

#define WSTRIDE 520  // bf16 elems per s_wd row (512 + 8 pad)

typedef __attribute__((ext_vector_type(8))) short short8;
typedef __attribute__((ext_vector_type(4))) float f32x4;

// ---------------- helpers ----------------

__device__ __forceinline__ unsigned short f2bf(float f) {   // RNE
    unsigned u = __float_as_uint(f);
    u += 0x7FFFu + ((u >> 16) & 1u);
    return (unsigned short)(u >> 16);
}

__device__ __forceinline__ void inv3(const double* m, double* o) {
    double a=m[0],b=m[1],c=m[2],d=m[3],e=m[4],f=m[5],g=m[6],h=m[7],i=m[8];
    double A  =  (e*i - f*h);
    double Bc = -(d*i - f*g);
    double Cc =  (d*h - e*g);
    double det = a*A + b*Bc + c*Cc;
    double inv = 1.0/det;
    o[0]=A*inv;            o[1]=-(b*i - c*h)*inv;  o[2]= (b*f - c*e)*inv;
    o[3]=Bc*inv;           o[4]= (a*i - c*g)*inv;  o[5]=-(a*f - c*d)*inv;
    o[6]=Cc*inv;           o[7]=-(a*h - b*g)*inv;  o[8]= (a*e - b*d)*inv;
}

// geometry for lane l (= depth) of pixel pix, camera bn. returns kept/vox.
__device__ __forceinline__ void geom_lane(const double* s_tf, int b, int pix, int l,
                                          bool& kept, int& vox) {
    const int hh = pix / FW, ww = pix % FW;
    const double fx = (double)((float)(ww * (703.0/43.0)));
    const double fy = (double)((float)(hh * 17.0));
    const double px = fx - s_tf[21], py = fy - s_tf[22], mz = -s_tf[23];
    const double qx0 = s_tf[ 9]*px + s_tf[10]*py + s_tf[11]*mz, qx1 = s_tf[11];
    const double qy0 = s_tf[12]*px + s_tf[13]*py + s_tf[14]*mz, qy1 = s_tf[14];
    const double qz0 = s_tf[15]*px + s_tf[16]*py + s_tf[17]*mz, qz1 = s_tf[17];
    const double ux0 = s_tf[0]*qx0 + s_tf[1]*qy0 + s_tf[2], ux1 = s_tf[0]*qx1 + s_tf[1]*qy1;
    const double uy0 = s_tf[3]*qx0 + s_tf[4]*qy0 + s_tf[5], uy1 = s_tf[3]*qx1 + s_tf[4]*qy1;
    const double uz0 = s_tf[6]*qx0 + s_tf[7]*qy0 + s_tf[8], uz1 = s_tf[6]*qx1 + s_tf[7]*qy1;
    const double t0 = s_tf[18], t1 = s_tf[19], t2 = s_tf[20];

    const double DXD = (double)0.8f;
    const double LOX = (double)(-50.8f) - DXD*0.5;
    const double LOY = LOX;
    const double DZD = 20.0;
    const double LOZ = -10.0;

    kept = false; vox = 0;
    if (l < Dd) {
        double fz = 4.0 + (double)l;
        double qz = qz0 + qz1*fz;
        double sx = qz*(ux0 + ux1*fz) + t0;
        double sy = qz*(uy0 + uy1*fz) + t1;
        double sz = qz*(uz0 + uz1*fz) + t2;
        int gx = (int)((sx - LOX) / DXD);
        int gy = (int)((sy - LOY) / DXD);
        int gz = (int)((sz - LOZ) / DZD);
        kept = (gx>=0) & (gx<NXX) & (gy>=0) & (gy<NYY) & (gz>=0) & (gz<NZZ);
        vox  = (((b*NZZ + gz)*NYY + gy)*NXX + gx);
    }
}

// ---------------- kernel P: prep = x->bf16 fragment layout + Wd->bf16 + tf --------
__global__ __launch_bounds__(256) void prep_kernel(
    const float* __restrict__ rots, const float* __restrict__ trans,
    const float* __restrict__ intrins, const float* __restrict__ post_rots,
    const float* __restrict__ post_trans, const float* __restrict__ Wd,
    const float* __restrict__ x,
    double* __restrict__ tf, unsigned short* __restrict__ WdB,
    unsigned short* __restrict__ xB)
{
    const int t = threadIdx.x;
    if (blockIdx.x < 2112) {
        __shared__ float s_x[64*65];
        const int p    = blockIdx.x;
        const int bn   = p / 88;
        const int r    = p % 88;
        const int kg   = r / 11;          // 0..7 (64 k each)
        const int tile = r % 11;
        const int pix0 = tile * 64;

        const float* src = x + ((size_t)bn*CIN + kg*64)*NPIX + pix0;
        #pragma unroll
        for (int i = 0; i < 16; i++) {
            int idx = i*256 + t;
            int k  = idx >> 6;
            int px = idx & 63;
            s_x[k*65 + px] = src[(size_t)k*NPIX + px];
        }
        __syncthreads();

        const int px  = t & 63;
        #pragma unroll
        for (int pass = 0; pass < 2; pass++) {
            int k8l = (t >> 6) + 4*pass;          // 0..7
            unsigned pk[4];
            #pragma unroll
            for (int i = 0; i < 4; i++) {
                float a = s_x[(k8l*8 + 2*i    )*65 + px];
                float c = s_x[(k8l*8 + 2*i + 1)*65 + px];
                pk[i] = (unsigned)f2bf(a) | ((unsigned)f2bf(c) << 16);
            }
            unsigned* dst = (unsigned*)&xB[(((size_t)(bn*64 + kg*8 + k8l))*NPIX + pix0 + px)*8];
            *(uint4*)dst = make_uint4(pk[0], pk[1], pk[2], pk[3]);
        }
    } else {
        int b2 = blockIdx.x - 2112;
        int idx = b2*256 + t;
        if (idx < 128*CIN) {
            int o = idx / CIN;
            WdB[idx] = (o < NO) ? f2bf(Wd[idx]) : (unsigned short)0;
        }
        if (b2 == 0 && t < B_*N_) {
            int bn = t;
            double k[9], pr[9], r[9], ik[9], ipr[9], c[9];
            for (int i=0;i<9;i++) { k[i]=intrins[bn*9+i]; pr[i]=post_rots[bn*9+i]; r[i]=rots[bn*9+i]; }
            inv3(k, ik);
            inv3(pr, ipr);
            for (int i=0;i<3;i++)
                for (int j=0;j<3;j++) {
                    double s = 0.0;
                    for (int kk=0;kk<3;kk++) s += r[i*3+kk]*ik[kk*3+j];
                    c[i*3+j] = s;
                }
            double* o = tf + bn*24;
            for (int i=0;i<9;i++) o[i]   = c[i];
            for (int i=0;i<9;i++) o[9+i] = ipr[i];
            for (int i=0;i<3;i++) o[18+i] = (double)trans[bn*3+i];
            for (int i=0;i<3;i++) o[21+i] = (double)post_trans[bn*3+i];
        }
    }
}

// ---------------- kernel G: bf16 MFMA GEMM, barrier-free K-loop ----------------
__global__ __launch_bounds__(256) void gemm_kernel(
    const unsigned short* __restrict__ xB, const unsigned short* __restrict__ WdB,
    const float* __restrict__ bd,
    float* __restrict__ featD, float* __restrict__ featB)
{
    __shared__ unsigned short s_wd[32*WSTRIDE];   // 33.3 KB

    const int t    = threadIdx.x;
    const int l    = t & 63;
    const int wv   = t >> 6;
    const int col  = l & 15;
    const int quad = l >> 4;

    const int xcd = blockIdx.x & 7;
    const int q   = blockIdx.x >> 3;
    const int s   = q & 3;               // osplit
    const int pg  = q >> 2;
    const int p   = pg*8 + xcd;          // 0..263
    const int bn   = p / 11;
    const int tile = p % 11;
    const int pix0 = tile * 64;

    {
        const int o  = t >> 3;           // 0..31
        const int c8 = t & 7;
        const unsigned short* srcw = WdB + (size_t)(s*32 + o)*CIN;
        #pragma unroll
        for (int i = 0; i < 8; i++) {
            int k = c8*8 + i*64;
            *(uint4*)&s_wd[o*WSTRIDE + k] = *(const uint4*)&srcw[k];
        }
    }
    __syncthreads();

    f32x4 acc[2];
    acc[0] = (f32x4){0.f,0.f,0.f,0.f};
    acc[1] = (f32x4){0.f,0.f,0.f,0.f};

    const int pix = pix0 + wv*16 + col;
    const unsigned short* xbase = xB + (((size_t)(bn*64) )*NPIX)*8;

    #pragma unroll
    for (int ks = 0; ks < 16; ks++) {
        const int k8 = ks*4 + quad;
        short8 bfr = *(const short8*)&xbase[((size_t)k8*NPIX + pix)*8];
        #pragma unroll
        for (int j = 0; j < 2; j++) {
            short8 afr = *(const short8*)&s_wd[(j*16 + col)*WSTRIDE + ks*32 + quad*8];
            acc[j] = __builtin_amdgcn_mfma_f32_16x16x32_bf16(afr, bfr, acc[j], 0, 0, 0);
        }
    }

    const size_t prow = (size_t)(bn*NPIX + pix);
    #pragma unroll
    for (int j = 0; j < 2; j++) {
        #pragma unroll
        for (int rr = 0; rr < 4; rr++) {
            int o = (2*s + j)*16 + quad*4 + rr;
            if (o < Dd) {
                featD[prow*DSTR + o] = acc[j][rr] + bd[o];
            } else if (o < NO) {
                featB[prow*CT + (o - Dd)] = acc[j][rr] + bd[o];
            }
        }
    }
}

// ---------------- kernel S1: geometry -> 8-way sub-hist + per-point rank ----------
// key = vox*8 + (pix&7): hot-voxel contributors spread over 8 sub-bins.
__global__ __launch_bounds__(256) void geom_hist_kernel(
    const double* __restrict__ tf, int* __restrict__ hist8,
    int* __restrict__ rank_arr)
{
    __shared__ double s_tf[24];
    const int bid = (blockIdx.x & 7) * 528 + (blockIdx.x >> 3);   // XCD locality
    const int t   = threadIdx.x;
    const int l   = t & 63;
    const int wv  = t >> 6;
    const int bn  = bid / 176;
    const int pix = (bid % 176)*4 + wv;
    const int b   = bn / N_;

    if (t < 24) s_tf[t] = tf[bn*24 + t];
    __syncthreads();

    bool kept; int vox;
    geom_lane(s_tf, b, pix, l, kept, vox);
    if (kept) {
        int key = vox*8 + (pix & 7);
        int rank = atomicAdd(&hist8[key], 1);
        rank_arr[(size_t)(bn*NPIX + pix)*Dd + l] = rank;
    }
}

// ---------------- scan: 2048-block local scan + 1-block scan of block sums ---------
__global__ __launch_bounds__(256) void scan1_kernel(const int* __restrict__ hist8,
                                                    int* __restrict__ offs8,
                                                    int* __restrict__ bsum) {
    __shared__ int s[256];
    const int t = threadIdx.x;
    const int i = blockIdx.x*256 + t;
    int val = hist8[i];
    s[t] = val;
    __syncthreads();
    #pragma unroll
    for (int off = 1; off < 256; off <<= 1) {
        int u = (t >= off) ? s[t-off] : 0;
        __syncthreads();
        s[t] += u;
        __syncthreads();
    }
    offs8[i] = s[t] - val;                 // block-local exclusive
    if (t == 255) bsum[blockIdx.x] = s[255];
}

__global__ __launch_bounds__(1024) void scan2_kernel(int* __restrict__ bsum,
                                                     int* __restrict__ np) {
    __shared__ int s[1024];
    const int t = threadIdx.x;
    int a = bsum[2*t], b = bsum[2*t+1];
    s[t] = a + b;
    __syncthreads();
    #pragma unroll
    for (int off = 1; off < 1024; off <<= 1) {
        int u = (t >= off) ? s[t-off] : 0;
        __syncthreads();
        s[t] += u;
        __syncthreads();
    }
    int excl = s[t] - (a + b);
    bsum[2*t]   = excl;
    bsum[2*t+1] = excl + a;
    if (t == 1023) np[0] = s[1023];
}

// ---------------- kernel S2: softmax + geometry + atomic-free record scatter --------
__global__ __launch_bounds__(256) void sm_scatter_kernel(
    const float* __restrict__ featD, const double* __restrict__ tf,
    const int* __restrict__ offs8, const int* __restrict__ bsum,
    const int* __restrict__ rank_arr, uint2* __restrict__ rec)
{
    __shared__ double s_tf[24];
    const int bid = (blockIdx.x & 7) * 528 + (blockIdx.x >> 3);   // XCD locality
    const int t   = threadIdx.x;
    const int l   = t & 63;
    const int wv  = t >> 6;
    const int bn  = bid / 176;
    const int pix = (bid % 176)*4 + wv;
    const int b   = bn / N_;

    if (t < 24) s_tf[t] = tf[bn*24 + t];
    __syncthreads();

    const size_t prow = (size_t)(bn*NPIX + pix);

    // ---- softmax across lanes (d = lane, 41 active) ----
    float logit = (l < Dd) ? featD[prow*DSTR + l] : -3.0e38f;
    float mm = logit;
    #pragma unroll
    for (int off = 32; off > 0; off >>= 1) mm = fmaxf(mm, __shfl_xor(mm, off));
    float e = (l < Dd) ? expf(logit - mm) : 0.0f;
    float ssum = e;
    #pragma unroll
    for (int off = 32; off > 0; off >>= 1) ssum += __shfl_xor(ssum, off);
    const float wgt = e / ssum;

    // ---- geometry + position from offs8 + bsum + rank (no atomics) ----
    bool kept; int vox;
    geom_lane(s_tf, b, pix, l, kept, vox);
    if (kept) {
        int key = vox*8 + (pix & 7);
        int pos = offs8[key] + bsum[key >> 8] + rank_arr[prow*Dd + l];
        unsigned pk = ((unsigned)vox << 15) | (unsigned)prow;
        rec[pos] = make_uint2(pk, __float_as_uint(wgt));
    }
}

// ---------------- kernel E: balanced segmented gather -> scat[vox][ct] ----------------
__global__ __launch_bounds__(256) void gather_kernel(
    const uint2* __restrict__ rec, const int* __restrict__ np,
    const float* __restrict__ featB, float* __restrict__ scat)
{
    const int bid = (blockIdx.x & 7) * 339 + (blockIdx.x >> 3);   // XCD locality
    const int t  = threadIdx.x;
    const int wv = t >> 6;
    const int l  = t & 63;
    const int chunk = bid * 4 + wv;
    const int base  = chunk * 64;
    const int Np = np[0];                  // total valid points
    if (base >= Np) return;
    int cnt = Np - base; if (cnt > 64) cnt = 64;

    unsigned pk = 0; float w = 0.0f;
    if (l < cnt) { uint2 r = rec[base + l]; pk = r.x; w = __uint_as_float(r.y); }
    unsigned pkm = __shfl(pk, (l == 0) ? 0 : (l - 1));
    unsigned long long starts =
        __ballot((l > 0) && (l < cnt) && ((pk >> 15) != (pkm >> 15)));

    unsigned long long m = starts;
    int rs = 0;
    while (rs < cnt) {
        int re = m ? (__ffsll((unsigned long long)m) - 1) : cnt;
        if (m) m &= m - 1;
        float acc = 0.0f;
        for (int j = rs; j < re; j++) {
            unsigned pkj = __shfl(pk, j);
            float    wj  = __shfl(w, j);
            unsigned id  = pkj & 0x7FFFu;
            acc += wj * featB[(size_t)id * CT + l];
        }
        unsigned vrun = __shfl(pk, rs) >> 15;
        float* dst = scat + (size_t)vrun * CT + l;
        if (rs == 0 || re == cnt) {
            unsafeAtomicAdd(dst, acc);      // run may continue in adjacent chunk
        } else {
            *dst = acc;                     // voxel wholly owned by this chunk
        }
        rs = re;
    }
}

// ---------------- kernel F: transpose (b,pix,ct) -> (b,ct,pix) ----------------
__global__ __launch_bounds__(256) void transpose_k(const float* __restrict__ scat,
                                                   float* __restrict__ out) {
    __shared__ float tile[64][65];
    int b  = blockIdx.x >> 8;
    int t0 = (blockIdx.x & 255) * 64;
    const float* src = scat + (size_t)b * (NYY*NXX) * CT;
    #pragma unroll
    for (int i=0;i<16;i++) {
        int idx = threadIdx.x + i*256;
        int p = idx >> 6, c = idx & 63;
        tile[p][c] = src[(size_t)(t0+p)*CT + c];
    }
    __syncthreads();
    float* dst = out + (size_t)b * CT * (NYY*NXX);
    #pragma unroll
    for (int i=0;i<16;i++) {
        int idx = threadIdx.x + i*256;
        int c = idx >> 6, p = idx & 63;
        dst[(size_t)c*(NYY*NXX) + t0 + p] = tile[p][c];
    }
}

// ---------------- launcher ----------------
extern "C" void kernel_launch(void* const* d_in, const int* in_sizes, int n_in,
                              void* d_out, int out_size, void* d_ws, size_t ws_size,
                              hipStream_t stream) {
    const float* x          = (const float*)d_in[0];
    const float* rots       = (const float*)d_in[1];
    const float* trans      = (const float*)d_in[2];
    const float* intrins    = (const float*)d_in[3];
    const float* post_rots  = (const float*)d_in[4];
    const float* post_trans = (const float*)d_in[5];
    const float* Wd         = (const float*)d_in[6];
    const float* bd         = (const float*)d_in[7];
    float* out = (float*)d_out;

    char* ws = (char*)d_ws;
    float*          featB  = (float*)ws;          ws += (size_t)B_*N_*NPIX*CT*4;    // 4.33 MB
    float*          featD  = (float*)ws;          ws += (size_t)B_*N_*NPIX*DSTR*4;  // 3.25 MB
    char*           Xreg   = ws;                  ws += (size_t)B_*N_*CIN*NPIX*2;   // 17.3 MB (xB, then scat)
    int*            rank_a = (int*)ws;            ws += (size_t)NPTS*4;             // 2.77 MB
    uint2*          rec    = (uint2*)ws;          ws += (size_t)NPTS*8;             // 5.54 MB
    int*            hist8  = (int*)ws;            ws += (size_t)NK*4;               // 2.0 MB
    int*            offs8  = (int*)ws;            ws += (size_t)NK*4;               // 2.0 MB
    int*            bsum   = (int*)ws;            ws += 2048*4;
    int*            np     = (int*)ws;            ws += 256;
    double*         tf     = (double*)ws;         ws += (size_t)B_*N_*24*8;         // 4.6 KB
    unsigned short* WdB    = (unsigned short*)ws; ws += (size_t)128*CIN*2;          // 0.13 MB

    unsigned short* xB   = (unsigned short*)Xreg;
    float*          scat = (float*)Xreg;   // reuses xB region after gemm

    hipMemsetAsync(hist8, 0, (size_t)NK*4, stream);
    prep_kernel<<<2368, 256, 0, stream>>>(rots, trans, intrins, post_rots, post_trans,
                                          Wd, x, tf, WdB, xB);
    gemm_kernel<<<1056, 256, 0, stream>>>(xB, WdB, bd, featD, featB);
    geom_hist_kernel<<<B_*N_*176, 256, 0, stream>>>(tf, hist8, rank_a);
    hipMemsetAsync(scat, 0, (size_t)TOT*CT*4, stream);      // xB dead after gemm
    scan1_kernel<<<NK/256, 256, 0, stream>>>(hist8, offs8, bsum);
    scan2_kernel<<<1, 1024, 0, stream>>>(bsum, np);
    sm_scatter_kernel<<<B_*N_*176, 256, 0, stream>>>(featD, tf, offs8, bsum, rank_a, rec);
    gather_kernel<<<2712, 256, 0, stream>>>(rec, np, featB, scat);
    transpose_k<<<B_*(NYY*NXX/64), 256, 0, stream>>>(scat, out);
}

// Round 13
// 208.915 us; speedup vs baseline: 1.5353x; 1.0573x over previous
//
#include <hip/hip_runtime.h>
#include <hip/hip_bf16.h>
#include <math.h>

#define B_   4
#define N_   6
#define CIN  512
#define CT   64
#define Dd   41
#define FH   16
#define FW   44
#define NPIX 704
#define NO   105
#define DSTR 48           // featD per-pixel stride
#define NXX  128
#define NYY  128
#define NZZ  1
#define TOT  (B_*NZZ*NYY*NXX)   // 65536
#define NPTS (B_*N_*Dd*NPIX)    // 692736
#define NCHUNK ((NPTS+63)/64)   // 10824

#define WSTRIDE 520  // bf16 elems per s_wd row (512 + 8 pad)

#define GEMM_BLOCKS 1056
#define GEOM_BLOCKS 4224

typedef __attribute__((ext_vector_type(8))) short short8;
typedef __attribute__((ext_vector_type(4))) float f32x4;

// ---------------- helpers ----------------

__device__ __forceinline__ unsigned short f2bf(float f) {   // RNE
    unsigned u = __float_as_uint(f);
    u += 0x7FFFu + ((u >> 16) & 1u);
    return (unsigned short)(u >> 16);
}

__device__ __forceinline__ void inv3(const double* m, double* o) {
    double a=m[0],b=m[1],c=m[2],d=m[3],e=m[4],f=m[5],g=m[6],h=m[7],i=m[8];
    double A  =  (e*i - f*h);
    double Bc = -(d*i - f*g);
    double Cc =  (d*h - e*g);
    double det = a*A + b*Bc + c*Cc;
    double inv = 1.0/det;
    o[0]=A*inv;            o[1]=-(b*i - c*h)*inv;  o[2]= (b*f - c*e)*inv;
    o[3]=Bc*inv;           o[4]= (a*i - c*g)*inv;  o[5]=-(a*f - c*d)*inv;
    o[6]=Cc*inv;           o[7]=-(a*h - b*g)*inv;  o[8]= (a*e - b*d)*inv;
}

// geometry for lane l (= depth) of pixel pix, camera bn. returns kept/vox.
__device__ __forceinline__ void geom_lane(const double* s_tf, int b, int pix, int l,
                                          bool& kept, int& vox) {
    const int hh = pix / FW, ww = pix % FW;
    const double fx = (double)((float)(ww * (703.0/43.0)));
    const double fy = (double)((float)(hh * 17.0));
    const double px = fx - s_tf[21], py = fy - s_tf[22], mz = -s_tf[23];
    const double qx0 = s_tf[ 9]*px + s_tf[10]*py + s_tf[11]*mz, qx1 = s_tf[11];
    const double qy0 = s_tf[12]*px + s_tf[13]*py + s_tf[14]*mz, qy1 = s_tf[14];
    const double qz0 = s_tf[15]*px + s_tf[16]*py + s_tf[17]*mz, qz1 = s_tf[17];
    const double ux0 = s_tf[0]*qx0 + s_tf[1]*qy0 + s_tf[2], ux1 = s_tf[0]*qx1 + s_tf[1]*qy1;
    const double uy0 = s_tf[3]*qx0 + s_tf[4]*qy0 + s_tf[5], uy1 = s_tf[3]*qx1 + s_tf[4]*qy1;
    const double uz0 = s_tf[6]*qx0 + s_tf[7]*qy0 + s_tf[8], uz1 = s_tf[6]*qx1 + s_tf[7]*qy1;
    const double t0 = s_tf[18], t1 = s_tf[19], t2 = s_tf[20];

    const double DXD = (double)0.8f;
    const double LOX = (double)(-50.8f) - DXD*0.5;
    const double LOY = LOX;
    const double DZD = 20.0;
    const double LOZ = -10.0;

    kept = false; vox = 0;
    if (l < Dd) {
        double fz = 4.0 + (double)l;
        double qz = qz0 + qz1*fz;
        double sx = qz*(ux0 + ux1*fz) + t0;
        double sy = qz*(uy0 + uy1*fz) + t1;
        double sz = qz*(uz0 + uz1*fz) + t2;
        int gx = (int)((sx - LOX) / DXD);
        int gy = (int)((sy - LOY) / DXD);
        int gz = (int)((sz - LOZ) / DZD);
        kept = (gx>=0) & (gx<NXX) & (gy>=0) & (gy<NYY) & (gz>=0) & (gz<NZZ);
        vox  = (((b*NZZ + gz)*NYY + gy)*NXX + gx);
    }
}

// ---------------- kernel P: prep = x->bf16 fragment layout + Wd->bf16 + tf --------
__global__ __launch_bounds__(256) void prep_kernel(
    const float* __restrict__ rots, const float* __restrict__ trans,
    const float* __restrict__ intrins, const float* __restrict__ post_rots,
    const float* __restrict__ post_trans, const float* __restrict__ Wd,
    const float* __restrict__ x,
    double* __restrict__ tf, unsigned short* __restrict__ WdB,
    unsigned short* __restrict__ xB)
{
    const int t = threadIdx.x;
    if (blockIdx.x < 2112) {
        __shared__ float s_x[64*65];
        const int p    = blockIdx.x;
        const int bn   = p / 88;
        const int r    = p % 88;
        const int kg   = r / 11;          // 0..7 (64 k each)
        const int tile = r % 11;
        const int pix0 = tile * 64;

        const float* src = x + ((size_t)bn*CIN + kg*64)*NPIX + pix0;
        #pragma unroll
        for (int i = 0; i < 16; i++) {
            int idx = i*256 + t;
            int k  = idx >> 6;
            int px = idx & 63;
            s_x[k*65 + px] = src[(size_t)k*NPIX + px];
        }
        __syncthreads();

        const int px  = t & 63;
        #pragma unroll
        for (int pass = 0; pass < 2; pass++) {
            int k8l = (t >> 6) + 4*pass;          // 0..7
            unsigned pk[4];
            #pragma unroll
            for (int i = 0; i < 4; i++) {
                float a = s_x[(k8l*8 + 2*i    )*65 + px];
                float c = s_x[(k8l*8 + 2*i + 1)*65 + px];
                pk[i] = (unsigned)f2bf(a) | ((unsigned)f2bf(c) << 16);
            }
            unsigned* dst = (unsigned*)&xB[(((size_t)(bn*64 + kg*8 + k8l))*NPIX + pix0 + px)*8];
            *(uint4*)dst = make_uint4(pk[0], pk[1], pk[2], pk[3]);
        }
    } else {
        int b2 = blockIdx.x - 2112;
        int idx = b2*256 + t;
        if (idx < 128*CIN) {
            int o = idx / CIN;
            WdB[idx] = (o < NO) ? f2bf(Wd[idx]) : (unsigned short)0;
        }
        if (b2 == 0 && t < B_*N_) {
            int bn = t;
            double k[9], pr[9], r[9], ik[9], ipr[9], c[9];
            for (int i=0;i<9;i++) { k[i]=intrins[bn*9+i]; pr[i]=post_rots[bn*9+i]; r[i]=rots[bn*9+i]; }
            inv3(k, ik);
            inv3(pr, ipr);
            for (int i=0;i<3;i++)
                for (int j=0;j<3;j++) {
                    double s = 0.0;
                    for (int kk=0;kk<3;kk++) s += r[i*3+kk]*ik[kk*3+j];
                    c[i*3+j] = s;
                }
            double* o = tf + bn*24;
            for (int i=0;i<9;i++) o[i]   = c[i];
            for (int i=0;i<9;i++) o[9+i] = ipr[i];
            for (int i=0;i<3;i++) o[18+i] = (double)trans[bn*3+i];
            for (int i=0;i<3;i++) o[21+i] = (double)post_trans[bn*3+i];
        }
    }
}

// ---------------- kernel GG: fused bf16 MFMA GEMM || geometry+hist ----------------
// blocks 0..1055: gemm (MFMA/LDS-bound). blocks 1056..5279: geometry + hist
// (fabric-atomic-bound). Disjoint pipes -> co-scheduled waves hide atomic latency.
__global__ __launch_bounds__(256) void gemm_geom_kernel(
    const unsigned short* __restrict__ xB, const unsigned short* __restrict__ WdB,
    const float* __restrict__ bd, const double* __restrict__ tf,
    float* __restrict__ featD, float* __restrict__ featB,
    int* __restrict__ hist, int* __restrict__ rank_arr)
{
    __shared__ unsigned short s_wd[32*WSTRIDE];   // 33.3 KB (gemm path)
    __shared__ double s_tf[24];                   // geom path

    const int t    = threadIdx.x;
    const int l    = t & 63;
    const int wv   = t >> 6;

    if (blockIdx.x < GEMM_BLOCKS) {
        // ================= GEMM path =================
        const int col  = l & 15;
        const int quad = l >> 4;
        const int xcd = blockIdx.x & 7;
        const int q   = blockIdx.x >> 3;
        const int s   = q & 3;               // osplit
        const int pg  = q >> 2;
        const int p   = pg*8 + xcd;          // 0..263
        const int bn   = p / 11;
        const int tile = p % 11;
        const int pix0 = tile * 64;

        {
            const int o  = t >> 3;           // 0..31
            const int c8 = t & 7;
            const unsigned short* srcw = WdB + (size_t)(s*32 + o)*CIN;
            #pragma unroll
            for (int i = 0; i < 8; i++) {
                int k = c8*8 + i*64;
                *(uint4*)&s_wd[o*WSTRIDE + k] = *(const uint4*)&srcw[k];
            }
        }
        __syncthreads();

        f32x4 acc[2];
        acc[0] = (f32x4){0.f,0.f,0.f,0.f};
        acc[1] = (f32x4){0.f,0.f,0.f,0.f};

        const int pix = pix0 + wv*16 + col;
        const unsigned short* xbase = xB + (((size_t)(bn*64))*NPIX)*8;

        #pragma unroll
        for (int ks = 0; ks < 16; ks++) {
            const int k8 = ks*4 + quad;
            short8 bfr = *(const short8*)&xbase[((size_t)k8*NPIX + pix)*8];
            #pragma unroll
            for (int j = 0; j < 2; j++) {
                short8 afr = *(const short8*)&s_wd[(j*16 + col)*WSTRIDE + ks*32 + quad*8];
                acc[j] = __builtin_amdgcn_mfma_f32_16x16x32_bf16(afr, bfr, acc[j], 0, 0, 0);
            }
        }

        const size_t prow = (size_t)(bn*NPIX + pix);
        #pragma unroll
        for (int j = 0; j < 2; j++) {
            #pragma unroll
            for (int rr = 0; rr < 4; rr++) {
                int o = (2*s + j)*16 + quad*4 + rr;
                if (o < Dd) {
                    featD[prow*DSTR + o] = acc[j][rr] + bd[o];
                } else if (o < NO) {
                    featB[prow*CT + (o - Dd)] = acc[j][rr] + bd[o];
                }
            }
        }
    } else {
        // ================= geometry + hist path =================
        const int bid2 = blockIdx.x - GEMM_BLOCKS;                 // 0..4223
        const int bid  = (bid2 & 7) * 528 + (bid2 >> 3);           // XCD locality
        const int bn  = bid / 176;
        const int pix = (bid % 176)*4 + wv;
        const int b   = bn / N_;

        if (t < 24) s_tf[t] = tf[bn*24 + t];
        __syncthreads();

        bool kept; int vox;
        geom_lane(s_tf, b, pix, l, kept, vox);
        if (kept) {
            int rank = atomicAdd(&hist[vox], 1);
            rank_arr[(size_t)(bn*NPIX + pix)*Dd + l] = rank;
        }
    }
}

// ---------------- scan: 256-block local scan + 1-block scan of block sums ---------
__global__ __launch_bounds__(256) void scan1_kernel(const int* __restrict__ hist,
                                                    int* __restrict__ offs,
                                                    int* __restrict__ bsum) {
    __shared__ int s[256];
    const int t = threadIdx.x;
    const int i = blockIdx.x*256 + t;
    int val = hist[i];
    s[t] = val;
    __syncthreads();
    #pragma unroll
    for (int off = 1; off < 256; off <<= 1) {
        int u = (t >= off) ? s[t-off] : 0;
        __syncthreads();
        s[t] += u;
        __syncthreads();
    }
    offs[i] = s[t] - val;                  // block-local exclusive
    if (t == 255) bsum[blockIdx.x] = s[255];
}

__global__ __launch_bounds__(256) void scan2_kernel(int* __restrict__ bsum,
                                                    int* __restrict__ np) {
    __shared__ int s[256];
    const int t = threadIdx.x;
    int v = bsum[t];
    s[t] = v;
    __syncthreads();
    #pragma unroll
    for (int off = 1; off < 256; off <<= 1) {
        int u = (t >= off) ? s[t-off] : 0;
        __syncthreads();
        s[t] += u;
        __syncthreads();
    }
    bsum[t] = s[t] - v;
    if (t == 255) np[0] = s[255];
}

// ---------------- kernel S2: softmax + geometry + atomic-free record scatter --------
__global__ __launch_bounds__(256) void sm_scatter_kernel(
    const float* __restrict__ featD, const double* __restrict__ tf,
    const int* __restrict__ offs, const int* __restrict__ bsum,
    const int* __restrict__ rank_arr, uint2* __restrict__ rec)
{
    __shared__ double s_tf[24];
    const int bid = (blockIdx.x & 7) * 528 + (blockIdx.x >> 3);   // XCD locality
    const int t   = threadIdx.x;
    const int l   = t & 63;
    const int wv  = t >> 6;
    const int bn  = bid / 176;
    const int pix = (bid % 176)*4 + wv;
    const int b   = bn / N_;

    if (t < 24) s_tf[t] = tf[bn*24 + t];
    __syncthreads();

    const size_t prow = (size_t)(bn*NPIX + pix);

    // ---- softmax across lanes (d = lane, 41 active) ----
    float logit = (l < Dd) ? featD[prow*DSTR + l] : -3.0e38f;
    float mm = logit;
    #pragma unroll
    for (int off = 32; off > 0; off >>= 1) mm = fmaxf(mm, __shfl_xor(mm, off));
    float e = (l < Dd) ? expf(logit - mm) : 0.0f;
    float ssum = e;
    #pragma unroll
    for (int off = 32; off > 0; off >>= 1) ssum += __shfl_xor(ssum, off);
    const float wgt = e / ssum;

    // ---- geometry + position from offs + bsum + rank (no atomics) ----
    bool kept; int vox;
    geom_lane(s_tf, b, pix, l, kept, vox);
    if (kept) {
        int pos = offs[vox] + bsum[vox >> 8] + rank_arr[prow*Dd + l];
        unsigned pk = ((unsigned)vox << 15) | (unsigned)prow;
        rec[pos] = make_uint2(pk, __float_as_uint(wgt));
    }
}

// ---------------- kernel E: balanced segmented gather -> scat[vox][ct] ----------------
__global__ __launch_bounds__(256) void gather_kernel(
    const uint2* __restrict__ rec, const int* __restrict__ np,
    const float* __restrict__ featB, float* __restrict__ scat)
{
    const int bid = (blockIdx.x & 7) * 339 + (blockIdx.x >> 3);   // XCD locality
    const int t  = threadIdx.x;
    const int wv = t >> 6;
    const int l  = t & 63;
    const int chunk = bid * 4 + wv;
    const int base  = chunk * 64;
    const int Np = np[0];                  // total valid points
    if (base >= Np) return;
    int cnt = Np - base; if (cnt > 64) cnt = 64;

    unsigned pk = 0; float w = 0.0f;
    if (l < cnt) { uint2 r = rec[base + l]; pk = r.x; w = __uint_as_float(r.y); }
    unsigned pkm = __shfl(pk, (l == 0) ? 0 : (l - 1));
    unsigned long long starts =
        __ballot((l > 0) && (l < cnt) && ((pk >> 15) != (pkm >> 15)));

    unsigned long long m = starts;
    int rs = 0;
    while (rs < cnt) {
        int re = m ? (__ffsll((unsigned long long)m) - 1) : cnt;
        if (m) m &= m - 1;
        float acc = 0.0f;
        for (int j = rs; j < re; j++) {
            unsigned pkj = __shfl(pk, j);
            float    wj  = __shfl(w, j);
            unsigned id  = pkj & 0x7FFFu;
            acc += wj * featB[(size_t)id * CT + l];
        }
        unsigned vrun = __shfl(pk, rs) >> 15;
        float* dst = scat + (size_t)vrun * CT + l;
        if (rs == 0 || re == cnt) {
            unsafeAtomicAdd(dst, acc);      // run may continue in adjacent chunk
        } else {
            *dst = acc;                     // voxel wholly owned by this chunk
        }
        rs = re;
    }
}

// ---------------- kernel F: transpose (b,pix,ct) -> (b,ct,pix) ----------------
__global__ __launch_bounds__(256) void transpose_k(const float* __restrict__ scat,
                                                   float* __restrict__ out) {
    __shared__ float tile[64][65];
    int b  = blockIdx.x >> 8;
    int t0 = (blockIdx.x & 255) * 64;
    const float* src = scat + (size_t)b * (NYY*NXX) * CT;
    #pragma unroll
    for (int i=0;i<16;i++) {
        int idx = threadIdx.x + i*256;
        int p = idx >> 6, c = idx & 63;
        tile[p][c] = src[(size_t)(t0+p)*CT + c];
    }
    __syncthreads();
    float* dst = out + (size_t)b * CT * (NYY*NXX);
    #pragma unroll
    for (int i=0;i<16;i++) {
        int idx = threadIdx.x + i*256;
        int c = idx >> 6, p = idx & 63;
        dst[(size_t)c*(NYY*NXX) + t0 + p] = tile[p][c];
    }
}

// ---------------- launcher ----------------
extern "C" void kernel_launch(void* const* d_in, const int* in_sizes, int n_in,
                              void* d_out, int out_size, void* d_ws, size_t ws_size,
                              hipStream_t stream) {
    const float* x          = (const float*)d_in[0];
    const float* rots       = (const float*)d_in[1];
    const float* trans      = (const float*)d_in[2];
    const float* intrins    = (const float*)d_in[3];
    const float* post_rots  = (const float*)d_in[4];
    const float* post_trans = (const float*)d_in[5];
    const float* Wd         = (const float*)d_in[6];
    const float* bd         = (const float*)d_in[7];
    float* out = (float*)d_out;

    char* ws = (char*)d_ws;
    float*          featB  = (float*)ws;          ws += (size_t)B_*N_*NPIX*CT*4;    // 4.33 MB
    float*          featD  = (float*)ws;          ws += (size_t)B_*N_*NPIX*DSTR*4;  // 3.25 MB
    char*           Xreg   = ws;                  ws += (size_t)B_*N_*CIN*NPIX*2;   // 17.3 MB (xB, then scat)
    int*            rank_a = (int*)ws;            ws += (size_t)NPTS*4;             // 2.77 MB
    uint2*          rec    = (uint2*)ws;          ws += (size_t)NPTS*8;             // 5.54 MB
    int*            hist   = (int*)ws;            ws += (size_t)TOT*4;              // 0.26 MB
    int*            offs   = (int*)ws;            ws += (size_t)TOT*4;              // 0.26 MB
    int*            bsum   = (int*)ws;            ws += 256*4;
    int*            np     = (int*)ws;            ws += 256;
    double*         tf     = (double*)ws;         ws += (size_t)B_*N_*24*8;         // 4.6 KB
    unsigned short* WdB    = (unsigned short*)ws; ws += (size_t)128*CIN*2;          // 0.13 MB

    unsigned short* xB   = (unsigned short*)Xreg;
    float*          scat = (float*)Xreg;   // reuses xB region after fused kernel

    hipMemsetAsync(hist, 0, (size_t)TOT*4, stream);
    prep_kernel<<<2368, 256, 0, stream>>>(rots, trans, intrins, post_rots, post_trans,
                                          Wd, x, tf, WdB, xB);
    gemm_geom_kernel<<<GEMM_BLOCKS + GEOM_BLOCKS, 256, 0, stream>>>(
        xB, WdB, bd, tf, featD, featB, hist, rank_a);
    hipMemsetAsync(scat, 0, (size_t)TOT*CT*4, stream);      // xB dead after fused
    scan1_kernel<<<TOT/256, 256, 0, stream>>>(hist, offs, bsum);
    scan2_kernel<<<1, 256, 0, stream>>>(bsum, np);
    sm_scatter_kernel<<<B_*N_*176, 256, 0, stream>>>(featD, tf, offs, bsum, rank_a, rec);
    gather_kernel<<<2712, 256, 0, stream>>>(rec, np, featB, scat);
    transpose_k<<<B_*(NYY*NXX/64), 256, 0, stream>>>(scat, out);
}